// Round 3
// baseline (15430.347 us; speedup 1.0000x reference)
//
#include <hip/hip_runtime.h>
#include <math.h>

// Problem constants (fixed by reference)
#define T   1024
#define NB  16
#define HD  512

// ws layout (float offsets)
#define OFF_RING 0                          // u64 ring[2][4][16][512] = 512 KB (131072 floats)
#define OFF_HH   131072                     // h_hist [2][T][NB][HD] = 16,777,216 floats
#define OFF_SH   (OFF_HH + 16777216)        // SH [16384][512] = 8,388,608 floats
#define OFF_SEGP (OFF_SH + 8388608)         // [16384]
#define OFF_GCTX (OFF_SEGP + 16384)         // [16][1024]
#define OFF_SEL  (OFF_GCTX + 16384)         // ints [16][12]

typedef unsigned long long u64;

__device__ __forceinline__ float sigmoidf_(float x){ return 1.0f/(1.0f + __expf(-x)); }
// fast tanh via exp2-based __expf; |err| ~1e-7, graceful saturation at +/-1
__device__ __forceinline__ float tanhf_(float x){ return 1.0f - 2.0f/(1.0f + __expf(2.0f*x)); }

// ---------------------------------------------------------------------------
// Persistent bidirectional LSTM. grid=256 wgs (1 per CU), block=256.
// wg -> (dir = wg&1, slice = wg>>1 of 4 hidden units). Weights in VGPRs.
//
// Sync = tag-embedded data (no flags, no fences):
//   producer (wave0): computes h, stores (h,f32 | tag=s+1) as ONE atomic u64
//     into ring slot s&3 (fire-and-forget, sc1 -> LLC).
//   consumer: loads all 64 pairs it needs with relaxed-AGENT u64 loads and
//     retries until every tag == s. The poll IS the data load: one LLC round
//     trip after production instead of {vmcnt ack, flag store, poll, h load}.
//   Ring depth 4 is safe: a wg at step s implies all wgs >= s-1 (data dep),
//   so the slot being overwritten (s-4) has no live readers (they'd be at s-3).
//   Replays: launch memsets the 512 KB ring, so every replay re-syncs honestly.
// x-gather (instr -> emb row, a dependent chain) is prefetched 1 step ahead.
// ---------------------------------------------------------------------------
__global__ __launch_bounds__(256, 1)
void lstm_kernel(const int* __restrict__ instr, const float* __restrict__ emb,
                 const float* __restrict__ wih_f, const float* __restrict__ whh_f,
                 const float* __restrict__ bih_f, const float* __restrict__ bhh_f,
                 const float* __restrict__ wih_b, const float* __restrict__ whh_b,
                 const float* __restrict__ bih_b, const float* __restrict__ bhh_b,
                 float* __restrict__ ws)
{
    u64* ring = (u64*)ws;             // [2][4][16][512]
    float* h_hist = ws + OFF_HH;

    const int wg    = blockIdx.x;     // 0..255
    const int dir   = wg & 1;
    const int slice = wg >> 1;        // 0..127
    const int U     = slice * 4;      // hidden-unit base

    u64* ringd = ring + (size_t)dir*4*16*512;

    const float* wih = dir ? wih_b : wih_f;
    const float* whh = dir ? whh_b : whh_f;
    const float* bih = dir ? bih_b : bih_f;
    const float* bhh = dir ? bhh_b : bhh_f;

    const int tid  = threadIdx.x;
    const int wid  = tid >> 6;
    const int lane = tid & 63;        // k-chunk id (8 k's per lane)
    const int bg   = wid >> 1;        // 0..1 : batches bg*8..bg*8+7
    const int rg   = wid & 1;         // 0..1 : local gate-rows rg*8..rg*8+7

    // Load weight slices into registers: local row (rg*8+ri), k = lane*8..+8
    float wi[64], wh[64];
#pragma unroll
    for (int ri = 0; ri < 8; ++ri){
        int rgl = rg*8 + ri;
        int gate = rgl >> 2, unit = rgl & 3;
        size_t row = (size_t)(gate*HD + U + unit) * HD + lane*8;
        float4 a0 = *(const float4*)(wih + row);
        float4 a1 = *(const float4*)(wih + row + 4);
        float4 b0 = *(const float4*)(whh + row);
        float4 b1 = *(const float4*)(whh + row + 4);
        wi[ri*8+0]=a0.x; wi[ri*8+1]=a0.y; wi[ri*8+2]=a0.z; wi[ri*8+3]=a0.w;
        wi[ri*8+4]=a1.x; wi[ri*8+5]=a1.y; wi[ri*8+6]=a1.z; wi[ri*8+7]=a1.w;
        wh[ri*8+0]=b0.x; wh[ri*8+1]=b0.y; wh[ri*8+2]=b0.z; wh[ri*8+3]=b0.w;
        wh[ri*8+4]=b1.x; wh[ri*8+5]=b1.y; wh[ri*8+6]=b1.z; wh[ri*8+7]=b1.w;
    }

    // Biases for owner lanes (tid<64 owns (b=tid>>2, u=tid&3))
    float bI, bF, bG, bO, cst = 0.0f;
    {
        int u = tid & 3;
        bI = bih[0*HD + U + u] + bhh[0*HD + U + u];
        bF = bih[1*HD + U + u] + bhh[1*HD + U + u];
        bG = bih[2*HD + U + u] + bhh[2*HD + U + u];
        bO = bih[3*HD + U + u] + bhh[3*HD + U + u];
    }

    __shared__ float gbuf[256];

    // reduce-scatter ownership: lane ends holding total of flat idx j=bitrev6(lane)
    const int jown = ((lane&1)<<5)|((lane&2)<<3)|((lane&4)<<1)|((lane&8)>>1)|((lane&16)>>3)|((lane&32)>>5);
    const int own_bi  = jown >> 3;
    const int own_rgl = rg*8 + (jown & 7);
    const int gslot   = (own_rgl >> 2)*64 + (bg*8 + own_bi)*4 + (own_rgl & 3);

    // Prologue: gather x for step 0
    float xc[64];
    {
        int t0 = dir ? (T-1) : 0;
#pragma unroll
        for (int bi = 0; bi < 8; ++bi){
            int b = bg*8 + bi;
            int idx = instr[b*T + t0];
            const float* px = emb + (size_t)idx*HD + lane*8;
            float4 x0 = *(const float4*)px;
            float4 x1 = *(const float4*)(px + 4);
            xc[bi*8+0]=x0.x; xc[bi*8+1]=x0.y; xc[bi*8+2]=x0.z; xc[bi*8+3]=x0.w;
            xc[bi*8+4]=x1.x; xc[bi*8+5]=x1.y; xc[bi*8+6]=x1.z; xc[bi*8+7]=x1.w;
        }
    }

    for (int s = 0; s < T; ++s){
        const int tp = dir ? (T-1-s) : s;   // original-time index for input AND h store

        // ---- issue next step's x-gather first (longest prefetch distance)
        float xn[64];
        if (s + 1 < T){
            int tn = dir ? (T-2-s) : (s+1);
#pragma unroll
            for (int bi = 0; bi < 8; ++bi){
                int b = bg*8 + bi;
                int idx = instr[b*T + tn];
                const float* px = emb + (size_t)idx*HD + lane*8;
                float4 x0 = *(const float4*)px;
                float4 x1 = *(const float4*)(px + 4);
                xn[bi*8+0]=x0.x; xn[bi*8+1]=x0.y; xn[bi*8+2]=x0.z; xn[bi*8+3]=x0.w;
                xn[bi*8+4]=x1.x; xn[bi*8+5]=x1.y; xn[bi*8+6]=x1.z; xn[bi*8+7]=x1.w;
            }
        }

        // ---- x-projection from prefetched xc
        float a[64];
#pragma unroll
        for (int j = 0; j < 64; ++j) a[j] = 0.0f;
#pragma unroll
        for (int bi = 0; bi < 8; ++bi){
#pragma unroll
            for (int kk = 0; kk < 8; ++kk){
                float xv = xc[bi*8+kk];
#pragma unroll
                for (int ri = 0; ri < 8; ++ri)
                    a[bi*8+ri] = fmaf(xv, wi[ri*8+kk], a[bi*8+ri]);
            }
        }

        // ---- h exchange: poll tag-embedded pairs, then h-projection
        if (s > 0){
            const int slot = (s-1) & 3;
            const unsigned int etag = (unsigned int)s;   // producer of step s-1 wrote tag s
            u64* hb = ringd + (size_t)slot*16*512;
            u64 p[64];
            for (;;){
#pragma unroll
                for (int bi = 0; bi < 8; ++bi){
                    u64* pb = hb + (size_t)(bg*8+bi)*512 + lane*8;
#pragma unroll
                    for (int q = 0; q < 8; ++q)
                        p[bi*8+q] = __hip_atomic_load(pb + q, __ATOMIC_RELAXED, __HIP_MEMORY_SCOPE_AGENT);
                }
                bool ok = true;
#pragma unroll
                for (int j = 0; j < 64; ++j)
                    ok &= ((unsigned int)(p[j] >> 32) == etag);
                if (__all(ok)) break;
            }
#pragma unroll
            for (int bi = 0; bi < 8; ++bi){
#pragma unroll
                for (int kk = 0; kk < 8; ++kk){
                    float hv = __uint_as_float((unsigned int)p[bi*8+kk]);
#pragma unroll
                    for (int ri = 0; ri < 8; ++ri)
                        a[bi*8+ri] = fmaf(hv, wh[ri*8+kk], a[bi*8+ri]);
                }
            }
        }

        // ---- reduce-scatter across 64 lanes (126 shfl + adds)
#pragma unroll
        for (int m = 0; m < 6; ++m){
            const int half = 32 >> m;
            const bool up = (lane >> m) & 1;
#pragma unroll
            for (int j = 0; j < 32; ++j){
                if (j < half){
                    float lo = a[j], hi = a[j+half];
                    float rlo = __shfl_xor(lo, 1<<m, 64);
                    float rhi = __shfl_xor(hi, 1<<m, 64);
                    a[j] = up ? (hi + rhi) : (lo + rlo);
                }
            }
        }

        gbuf[gslot] = a[0];
        __syncthreads();

        if (tid < 64){   // wave-uniform branch: wave0 only
            float iv = sigmoidf_(gbuf[      tid] + bI);
            float fv = sigmoidf_(gbuf[ 64 + tid] + bF);
            float gv = tanhf_  (gbuf[128 + tid] + bG);
            float ov = sigmoidf_(gbuf[192 + tid] + bO);
            cst = fv*cst + iv*gv;
            float hv = ov * tanhf_(cst);
            int b = tid >> 2, u = tid & 3;
            // plain cached store for the epilogue kernels (dispatch-boundary visibility)
            h_hist[((size_t)(dir*T + tp)*NB + b)*HD + U + u] = hv;
            // tagged pair for same-kernel consumers: ONE atomic 8B store = data+flag
            u64 pv = ((u64)(unsigned int)(s+1) << 32) | (u64)__float_as_uint(hv);
            __hip_atomic_store(ringd + (size_t)(s&3)*16*512 + (size_t)b*512 + U + u, pv,
                               __ATOMIC_RELAXED, __HIP_MEMORY_SCOPE_AGENT);
        }
        // no barrier needed after: next step's gbuf writes are causally ordered
        // behind this step's ring stores (consumers validate before writing gbuf),
        // and wave0's ring store is data-dependent on its gbuf reads.

        if (s + 1 < T){
#pragma unroll
            for (int j = 0; j < 64; ++j) xc[j] = xn[j];
        }
    }
}

// ---------------------------------------------------------------------------
// SH = relu(enc @ ws1.T + bs1)   M=16384 N=512 K=1024, fp32 64x64x16 tiles
// ---------------------------------------------------------------------------
__global__ __launch_bounds__(256, 2)
void seg_gemm(const float* __restrict__ ws_, const float* __restrict__ ws1,
              const float* __restrict__ bs1)
{
    const float* h_hist = ws_ + OFF_HH;
    float* SH = (float*)(ws_ + OFF_SH);
    __shared__ float As[64][17];
    __shared__ float Bs[64][17];
    const int m0 = blockIdx.x * 64;
    const int n0 = blockIdx.y * 64;
    const int tid = threadIdx.x;
    const int r  = tid >> 2;
    const int kq = (tid & 3) * 4;
    const int ty = tid >> 4, tx = tid & 15;
    const int bI = m0 >> 10;          // tile stays inside one batch
    const int t0 = m0 & 1023;

    float acc[4][4];
#pragma unroll
    for (int i=0;i<4;i++)
#pragma unroll
        for (int j=0;j<4;j++) acc[i][j]=0.0f;

    for (int kb = 0; kb < 1024; kb += 16){
        int kk = kb + kq;
        const float* ap = (kk < 512)
            ? h_hist + ((size_t)(t0 + r)*NB + bI)*HD + kk
            : h_hist + ((size_t)(T + t0 + r)*NB + bI)*HD + (kk - 512);
        float4 av = *(const float4*)ap;
        As[r][kq+0]=av.x; As[r][kq+1]=av.y; As[r][kq+2]=av.z; As[r][kq+3]=av.w;
        float4 bv = *(const float4*)(ws1 + (size_t)(n0 + r)*1024 + kk);
        Bs[r][kq+0]=bv.x; Bs[r][kq+1]=bv.y; Bs[r][kq+2]=bv.z; Bs[r][kq+3]=bv.w;
        __syncthreads();
#pragma unroll
        for (int k2 = 0; k2 < 16; ++k2){
            float av_[4], bv_[4];
#pragma unroll
            for (int i=0;i<4;i++) av_[i] = As[ty*4+i][k2];
#pragma unroll
            for (int j=0;j<4;j++) bv_[j] = Bs[tx*4+j][k2];
#pragma unroll
            for (int i=0;i<4;i++)
#pragma unroll
                for (int j=0;j<4;j++) acc[i][j] = fmaf(av_[i], bv_[j], acc[i][j]);
        }
        __syncthreads();
    }
#pragma unroll
    for (int i=0;i<4;i++){
        int m = m0 + ty*4 + i;
#pragma unroll
        for (int j=0;j<4;j++){
            int n = n0 + tx*4 + j;
            SH[(size_t)m*512 + n] = fmaxf(acc[i][j] + bs1[n], 0.0f);
        }
    }
}

// ---------------------------------------------------------------------------
// scores -> sigmoid -> seg_probs (ws copy + d_out)
// ---------------------------------------------------------------------------
__global__ void seg_score(const float* __restrict__ ws_, const float* __restrict__ ws2,
                          const float* __restrict__ bs2, float* __restrict__ dout)
{
    const float* SH = ws_ + OFF_SH;
    float* segp = (float*)(ws_ + OFF_SEGP);
    int row  = blockIdx.x*4 + (threadIdx.x >> 6);
    int lane = threadIdx.x & 63;
    const float* p = SH + (size_t)row*512 + lane*8;
    const float* q = ws2 + lane*8;
    float4 a0=*(const float4*)p, a1=*(const float4*)(p+4);
    float4 b0=*(const float4*)q, b1=*(const float4*)(q+4);
    float ssum = a0.x*b0.x + a0.y*b0.y + a0.z*b0.z + a0.w*b0.w
               + a1.x*b1.x + a1.y*b1.y + a1.z*b1.z + a1.w*b1.w;
#pragma unroll
    for (int m=1;m<64;m<<=1) ssum += __shfl_xor(ssum, m, 64);
    if (lane == 0){
        float z = ssum + bs2[0];
        float pr = 1.0f/(1.0f + __expf(-z));
        segp[row] = pr;
        dout[81920 + row] = pr;
    }
}

// ---------------------------------------------------------------------------
// Per-batch: mask scan (count, first-10 idx), pooled -> gctx
// ---------------------------------------------------------------------------
__global__ void select_gctx(float* __restrict__ ws_, const float* __restrict__ wgm,
                            const float* __restrict__ bgv)
{
    const float* h_hist = ws_ + OFF_HH;
    const float* segp   = ws_ + OFF_SEGP;
    float* gctx = ws_ + OFF_GCTX;
    int* sel = (int*)(ws_ + OFF_SEL);
    int b = blockIdx.x, tid = threadIdx.x;
    __shared__ unsigned char flag[1024];
    __shared__ float pool[1024];
    for (int j = tid; j < 1024; j += 256){
        flag[j] = segp[b*1024 + j] > 0.5f ? 1 : 0;
        pool[j] = (j < 512) ? h_hist[((size_t)1023*NB + b)*HD + j]
                            : h_hist[((size_t)T*NB + b)*HD + (j - 512)];
    }
    __syncthreads();
    if (tid == 0){
        int c = 0;
        int tmp[10];
        for (int j = 0; j < 10; ++j) tmp[j] = 0;
        for (int t = 0; t < 1024; ++t){
            if (flag[t]){ if (c < 10) tmp[c] = t; c++; }
        }
        for (int j = 0; j < 10; ++j) sel[b*12 + j] = tmp[j];
        sel[b*12 + 10] = c;
        sel[b*12 + 11] = 0;
    }
    __syncthreads();
    for (int n = tid; n < 1024; n += 256){
        float acc = bgv[n];
        const float* wr = wgm + (size_t)n*1024;
        for (int k = 0; k < 1024; k += 4){
            acc += wr[k]*pool[k] + wr[k+1]*pool[k+1] + wr[k+2]*pool[k+2] + wr[k+3]*pool[k+3];
        }
        gctx[b*1024 + n] = acc;
    }
}

// ---------------------------------------------------------------------------
// Decoder: one block per (b,slot)
// ---------------------------------------------------------------------------
__global__ void decode(const float* __restrict__ ws_, const float* __restrict__ wd1,
                       const float* __restrict__ bd1, const float* __restrict__ wd2,
                       const float* __restrict__ bd2, float* __restrict__ dout)
{
    const float* h_hist = ws_ + OFF_HH;
    const float* gctx   = ws_ + OFF_GCTX;
    const int* sel = (const int*)(ws_ + OFF_SEL);
    int blk = blockIdx.x;
    int b = blk / 10, slot = blk % 10;
    int tid = threadIdx.x;
    int count = sel[b*12 + 10];
    int nval = count < 10 ? count : 10;
    bool empty = (count == 0);
    float* outp = dout + (size_t)(b*10 + slot)*512;
    if (slot >= nval && !(empty && slot == 0)){
        for (int n = tid; n < 512; n += 256) outp[n] = 0.0f;
        return;
    }
    __shared__ float row[1024];
    __shared__ float dh[512];
    if (empty){
        for (int j = tid; j < 1024; j += 256) row[j] = gctx[b*1024 + j];
    } else {
        int t = sel[b*12 + slot];
        for (int j = tid; j < 1024; j += 256)
            row[j] = (j < 512) ? h_hist[((size_t)t*NB + b)*HD + j]
                               : h_hist[((size_t)(T + t)*NB + b)*HD + (j-512)];
    }
    __syncthreads();
    for (int d = tid; d < 512; d += 256){
        float acc = bd1[d];
        const float* wr = wd1 + (size_t)d*1024;
        for (int k = 0; k < 1024; ++k) acc += wr[k]*row[k];
        dh[d] = fmaxf(acc, 0.0f);
    }
    __syncthreads();
    for (int n = tid; n < 512; n += 256){
        float acc = bd2[n];
        const float* wr = wd2 + (size_t)n*512;
        for (int k = 0; k < 512; ++k) acc += wr[k]*dh[k];
        outp[n] = acc;
    }
}

extern "C" void kernel_launch(void* const* d_in, const int* in_sizes, int n_in,
                              void* d_out, int out_size, void* d_ws, size_t ws_size,
                              hipStream_t stream)
{
    const int*   instr = (const int*)d_in[0];
    const float* emb   = (const float*)d_in[1];
    const float* wih_f = (const float*)d_in[2];
    const float* whh_f = (const float*)d_in[3];
    const float* bih_f = (const float*)d_in[4];
    const float* bhh_f = (const float*)d_in[5];
    const float* wih_b = (const float*)d_in[6];
    const float* whh_b = (const float*)d_in[7];
    const float* bih_b = (const float*)d_in[8];
    const float* bhh_b = (const float*)d_in[9];
    const float* wg_   = (const float*)d_in[10];
    const float* bg_   = (const float*)d_in[11];
    const float* ws1   = (const float*)d_in[12];
    const float* bs1   = (const float*)d_in[13];
    const float* ws2   = (const float*)d_in[14];
    const float* bs2   = (const float*)d_in[15];
    const float* wd1   = (const float*)d_in[16];
    const float* bd1   = (const float*)d_in[17];
    const float* wd2   = (const float*)d_in[18];
    const float* bd2   = (const float*)d_in[19];
    float* out = (float*)d_out;
    float* ws  = (float*)d_ws;

    // zero the 512 KB tag ring each call (replays re-sync honestly; ~0.1 us)
    hipMemsetAsync(d_ws, 0, (size_t)2*4*16*512*8, stream);

    hipLaunchKernelGGL(lstm_kernel, dim3(256), dim3(256), 0, stream,
                       instr, emb, wih_f, whh_f, bih_f, bhh_f,
                       wih_b, whh_b, bih_b, bhh_b, ws);
    hipLaunchKernelGGL(seg_gemm, dim3(256, 8), dim3(256), 0, stream, ws, ws1, bs1);
    hipLaunchKernelGGL(seg_score, dim3(4096), dim3(256), 0, stream, ws, ws2, bs2, out);
    hipLaunchKernelGGL(select_gctx, dim3(16), dim3(256), 0, stream, ws, wg_, bg_);
    hipLaunchKernelGGL(decode, dim3(160), dim3(256), 0, stream, ws, wd1, bd1, wd2, bd2, out);
}

// Round 4
// 4748.516 us; speedup vs baseline: 3.2495x; 3.2495x over previous
//
#include <hip/hip_runtime.h>
#include <math.h>

// Problem constants (fixed by reference)
#define T   1024
#define NB  16
#define HD  512

// ws layout (float offsets)
#define OFF_BAR  0                         // 256 ints: flag[2][128] step counters
#define OFF_HH   256                       // h_hist [2][T][NB][HD] = 16,777,216 floats
#define OFF_SH   (OFF_HH + 16777216)       // SH [16384][512] = 8,388,608 floats
#define OFF_SEGP (OFF_SH + 8388608)        // [16384]
#define OFF_GCTX (OFF_SEGP + 16384)        // [16][1024]
#define OFF_SEL  (OFF_GCTX + 16384)        // ints [16][12]

typedef unsigned long long u64;

__device__ __forceinline__ float sigmoidf_(float x){ return 1.0f/(1.0f + __expf(-x)); }
// fast tanh via exp2-based __expf; |err| ~1e-7, graceful saturation at +/-1
__device__ __forceinline__ float tanhf_(float x){ return 1.0f - 2.0f/(1.0f + __expf(2.0f*x)); }

// ---------------------------------------------------------------------------
// Persistent bidirectional LSTM. grid=256 wgs (1 per CU), block=512 (8 waves).
// wg -> (dir = wg&1, slice = wg>>1 of 4 hidden units). Weights in VGPRs.
// wave wid: bg=wid>>1 (4 batches), rg=wid&1 (8 gate-rows). Per thread a[32].
//
// Sync protocol (proven in round 2):
//   producer wave0: h stores = relaxed-AGENT 4B stores (sc1 -> LLC, bypass L2)
//     -> s_waitcnt vmcnt(0) -> flag[dir][slice]=s+1 (relaxed-AGENT store)
//   consumer wave0: polls 128 flags with relaxed-AGENT loads, __all, barrier.
// h READ is a plain cached float4 load (NEW): address (dir,t) is unique per
// step and only touched after the flags, so consumer L2 can't hold a stale
// copy (launch acquire invalidated pre-kernel lines; empirically proven by
// seg_gemm plain-reading sc1-written h_hist across replays). 16 wgs/XCD/dir
// share the 32KB h vector in their L2 -> coalesced, amortized broadcast
// instead of round 2's 0.5M uncoalesced 8B atomic transactions per step.
// ---------------------------------------------------------------------------
__global__ __launch_bounds__(512, 1)
void lstm_kernel(const int* __restrict__ instr, const float* __restrict__ emb,
                 const float* __restrict__ wih_f, const float* __restrict__ whh_f,
                 const float* __restrict__ bih_f, const float* __restrict__ bhh_f,
                 const float* __restrict__ wih_b, const float* __restrict__ whh_b,
                 const float* __restrict__ bih_b, const float* __restrict__ bhh_b,
                 float* __restrict__ ws)
{
    float* h_hist = ws + OFF_HH;
    int* flags = (int*)ws;            // flag[2][128]

    const int wg    = blockIdx.x;     // 0..255
    const int dir   = wg & 1;
    const int slice = wg >> 1;        // 0..127
    const int U     = slice * 4;      // hidden-unit base

    int* barf = flags + dir*128;

    const float* wih = dir ? wih_b : wih_f;
    const float* whh = dir ? whh_b : whh_f;
    const float* bih = dir ? bih_b : bih_f;
    const float* bhh = dir ? bhh_b : bhh_f;

    const int tid  = threadIdx.x;
    const int wid  = tid >> 6;        // 0..7
    const int lane = tid & 63;        // k-chunk id (8 k's per lane)
    const int bg   = wid >> 1;        // 0..3 : batches bg*4..bg*4+3
    const int rg   = wid & 1;         // 0..1 : local gate-rows rg*8..rg*8+7

    // Load weight slices into registers: local row (rg*8+ri), k = lane*8..+8
    float wi[64], wh[64];
#pragma unroll
    for (int ri = 0; ri < 8; ++ri){
        int rgl = rg*8 + ri;
        int gate = rgl >> 2, unit = rgl & 3;
        size_t row = (size_t)(gate*HD + U + unit) * HD + lane*8;
        float4 a0 = *(const float4*)(wih + row);
        float4 a1 = *(const float4*)(wih + row + 4);
        float4 b0 = *(const float4*)(whh + row);
        float4 b1 = *(const float4*)(whh + row + 4);
        wi[ri*8+0]=a0.x; wi[ri*8+1]=a0.y; wi[ri*8+2]=a0.z; wi[ri*8+3]=a0.w;
        wi[ri*8+4]=a1.x; wi[ri*8+5]=a1.y; wi[ri*8+6]=a1.z; wi[ri*8+7]=a1.w;
        wh[ri*8+0]=b0.x; wh[ri*8+1]=b0.y; wh[ri*8+2]=b0.z; wh[ri*8+3]=b0.w;
        wh[ri*8+4]=b1.x; wh[ri*8+5]=b1.y; wh[ri*8+6]=b1.z; wh[ri*8+7]=b1.w;
    }

    // Biases for owner lanes (tid<64 owns (b=tid>>2, u=tid&3))
    float bI, bF, bG, bO, cst = 0.0f;
    {
        int u = tid & 3;
        bI = bih[0*HD + U + u] + bhh[0*HD + U + u];
        bF = bih[1*HD + U + u] + bhh[1*HD + U + u];
        bG = bih[2*HD + U + u] + bhh[2*HD + U + u];
        bO = bih[3*HD + U + u] + bhh[3*HD + U + u];
    }

    __shared__ float gbuf[256];

    // reduce-scatter ownership (32 values, 5 xor stages + cross-half merge):
    // j = bit0*16 + bit1*8 + bit2*4 + bit3*2 + bit4*1  (bitrev5 of lane&31)
    const int jown = ((lane&1)<<4)|((lane&2)<<2)|(lane&4)|((lane&8)>>2)|((lane&16)>>4);
    const int own_bi  = jown >> 3;            // 0..3
    const int own_rgl = rg*8 + (jown & 7);    // 0..15
    const int gslot   = (own_rgl >> 2)*64 + (bg*4 + own_bi)*4 + (own_rgl & 3);

    for (int s = 0; s < T; ++s){
        const int tp = dir ? (T-1-s) : s;   // original-time index for input AND h store

        // ---- x gather + x-projection: independent of the barrier, hides latency
        float a[32];
#pragma unroll
        for (int j = 0; j < 32; ++j) a[j] = 0.0f;

#pragma unroll
        for (int bi = 0; bi < 4; ++bi){
            int b = bg*4 + bi;
            int idx = instr[b*T + tp];
            const float* px = emb + (size_t)idx*HD + lane*8;
            float4 x0 = *(const float4*)px;
            float4 x1 = *(const float4*)(px + 4);
            float xs[8] = {x0.x,x0.y,x0.z,x0.w,x1.x,x1.y,x1.z,x1.w};
#pragma unroll
            for (int kk = 0; kk < 8; ++kk){
                float xv = xs[kk];
#pragma unroll
                for (int ri = 0; ri < 8; ++ri)
                    a[bi*8+ri] = fmaf(xv, wi[ri*8+kk], a[bi*8+ri]);
            }
        }

        // ---- wait for step s-1 of all 128 wgs in this direction
        if (s > 0){
            if (wid == 0){
                for (;;){
                    int v0 = __hip_atomic_load((int*)(barf + lane),      __ATOMIC_RELAXED, __HIP_MEMORY_SCOPE_AGENT);
                    int v1 = __hip_atomic_load((int*)(barf + 64 + lane), __ATOMIC_RELAXED, __HIP_MEMORY_SCOPE_AGENT);
                    if (__all((v0 >= s) && (v1 >= s))) break;
                    __builtin_amdgcn_s_sleep(1);
                }
            }
            __syncthreads();

            // ---- h-projection: PLAIN cached loads (coalesced; L2-shared per XCD)
            const int tprev = dir ? (T - s) : (s - 1);
            const float* hbase = h_hist + (size_t)(dir*T + tprev)*NB*HD;
#pragma unroll
            for (int bi = 0; bi < 4; ++bi){
                int b = bg*4 + bi;
                const float* ph = hbase + (size_t)b*HD + lane*8;
                float4 h0 = *(const float4*)ph;
                float4 h1 = *(const float4*)(ph + 4);
                float hs[8] = {h0.x,h0.y,h0.z,h0.w,h1.x,h1.y,h1.z,h1.w};
#pragma unroll
                for (int kk = 0; kk < 8; ++kk){
                    float hv = hs[kk];
#pragma unroll
                    for (int ri = 0; ri < 8; ++ri)
                        a[bi*8+ri] = fmaf(hv, wh[ri*8+kk], a[bi*8+ri]);
                }
            }
        }

        // ---- reduce-scatter: 32 values over 64 lanes (5 stages + merge)
#pragma unroll
        for (int m = 0; m < 5; ++m){
            const int half = 16 >> m;
            const bool up = (lane >> m) & 1;
#pragma unroll
            for (int j = 0; j < 16; ++j){
                if (j < half){
                    float lo = a[j], hi = a[j+half];
                    float rlo = __shfl_xor(lo, 1<<m, 64);
                    float rhi = __shfl_xor(hi, 1<<m, 64);
                    a[j] = up ? (hi + rhi) : (lo + rlo);
                }
            }
        }
        a[0] += __shfl_xor(a[0], 32, 64);   // cross-half k merge

        if ((lane & 32) == 0) gbuf[gslot] = a[0];
        __syncthreads();

        if (tid < 64){   // wave-uniform branch: wave0 only
            float iv = sigmoidf_(gbuf[      tid] + bI);
            float fv = sigmoidf_(gbuf[ 64 + tid] + bF);
            float gv = tanhf_  (gbuf[128 + tid] + bG);
            float ov = sigmoidf_(gbuf[192 + tid] + bO);
            cst = fv*cst + iv*gv;
            float hv = ov * tanhf_(cst);
            int b = tid >> 2, u = tid & 3;
            // sc1 store: reaches LLC (bypasses local L2) before the flag
            __hip_atomic_store(&h_hist[((size_t)(dir*T + tp)*NB + b)*HD + U + u], hv,
                               __ATOMIC_RELAXED, __HIP_MEMORY_SCOPE_AGENT);
        }
        // order: h stores acked at LLC before flag store; no L2 flushes
        asm volatile("s_waitcnt vmcnt(0)" ::: "memory");
        __builtin_amdgcn_sched_barrier(0);
        if (tid == 0)
            __hip_atomic_store(barf + slice, s + 1, __ATOMIC_RELAXED, __HIP_MEMORY_SCOPE_AGENT);
        // no trailing barrier needed: gbuf WAR for step s+1 is ordered by the
        // post-poll __syncthreads (wave0 reaches it only after its gbuf reads).
    }
}

// ---------------------------------------------------------------------------
// SH = relu(enc @ ws1.T + bs1)   M=16384 N=512 K=1024, fp32 64x64x16 tiles
// ---------------------------------------------------------------------------
__global__ __launch_bounds__(256, 2)
void seg_gemm(const float* __restrict__ ws_, const float* __restrict__ ws1,
              const float* __restrict__ bs1)
{
    const float* h_hist = ws_ + OFF_HH;
    float* SH = (float*)(ws_ + OFF_SH);
    __shared__ float As[64][17];
    __shared__ float Bs[64][17];
    const int m0 = blockIdx.x * 64;
    const int n0 = blockIdx.y * 64;
    const int tid = threadIdx.x;
    const int r  = tid >> 2;
    const int kq = (tid & 3) * 4;
    const int ty = tid >> 4, tx = tid & 15;
    const int bI = m0 >> 10;          // tile stays inside one batch
    const int t0 = m0 & 1023;

    float acc[4][4];
#pragma unroll
    for (int i=0;i<4;i++)
#pragma unroll
        for (int j=0;j<4;j++) acc[i][j]=0.0f;

    for (int kb = 0; kb < 1024; kb += 16){
        int kk = kb + kq;
        const float* ap = (kk < 512)
            ? h_hist + ((size_t)(t0 + r)*NB + bI)*HD + kk
            : h_hist + ((size_t)(T + t0 + r)*NB + bI)*HD + (kk - 512);
        float4 av = *(const float4*)ap;
        As[r][kq+0]=av.x; As[r][kq+1]=av.y; As[r][kq+2]=av.z; As[r][kq+3]=av.w;
        float4 bv = *(const float4*)(ws1 + (size_t)(n0 + r)*1024 + kk);
        Bs[r][kq+0]=bv.x; Bs[r][kq+1]=bv.y; Bs[r][kq+2]=bv.z; Bs[r][kq+3]=bv.w;
        __syncthreads();
#pragma unroll
        for (int k2 = 0; k2 < 16; ++k2){
            float av_[4], bv_[4];
#pragma unroll
            for (int i=0;i<4;i++) av_[i] = As[ty*4+i][k2];
#pragma unroll
            for (int j=0;j<4;j++) bv_[j] = Bs[tx*4+j][k2];
#pragma unroll
            for (int i=0;i<4;i++)
#pragma unroll
                for (int j=0;j<4;j++) acc[i][j] = fmaf(av_[i], bv_[j], acc[i][j]);
        }
        __syncthreads();
    }
#pragma unroll
    for (int i=0;i<4;i++){
        int m = m0 + ty*4 + i;
#pragma unroll
        for (int j=0;j<4;j++){
            int n = n0 + tx*4 + j;
            SH[(size_t)m*512 + n] = fmaxf(acc[i][j] + bs1[n], 0.0f);
        }
    }
}

// ---------------------------------------------------------------------------
// scores -> sigmoid -> seg_probs (ws copy + d_out)
// ---------------------------------------------------------------------------
__global__ void seg_score(const float* __restrict__ ws_, const float* __restrict__ ws2,
                          const float* __restrict__ bs2, float* __restrict__ dout)
{
    const float* SH = ws_ + OFF_SH;
    float* segp = (float*)(ws_ + OFF_SEGP);
    int row  = blockIdx.x*4 + (threadIdx.x >> 6);
    int lane = threadIdx.x & 63;
    const float* p = SH + (size_t)row*512 + lane*8;
    const float* q = ws2 + lane*8;
    float4 a0=*(const float4*)p, a1=*(const float4*)(p+4);
    float4 b0=*(const float4*)q, b1=*(const float4*)(q+4);
    float ssum = a0.x*b0.x + a0.y*b0.y + a0.z*b0.z + a0.w*b0.w
               + a1.x*b1.x + a1.y*b1.y + a1.z*b1.z + a1.w*b1.w;
#pragma unroll
    for (int m=1;m<64;m<<=1) ssum += __shfl_xor(ssum, m, 64);
    if (lane == 0){
        float z = ssum + bs2[0];
        float pr = 1.0f/(1.0f + __expf(-z));
        segp[row] = pr;
        dout[81920 + row] = pr;
    }
}

// ---------------------------------------------------------------------------
// Per-batch: mask scan (count, first-10 idx), pooled -> gctx
// ---------------------------------------------------------------------------
__global__ void select_gctx(float* __restrict__ ws_, const float* __restrict__ wgm,
                            const float* __restrict__ bgv)
{
    const float* h_hist = ws_ + OFF_HH;
    const float* segp   = ws_ + OFF_SEGP;
    float* gctx = ws_ + OFF_GCTX;
    int* sel = (int*)(ws_ + OFF_SEL);
    int b = blockIdx.x, tid = threadIdx.x;
    __shared__ unsigned char flag[1024];
    __shared__ float pool[1024];
    for (int j = tid; j < 1024; j += 256){
        flag[j] = segp[b*1024 + j] > 0.5f ? 1 : 0;
        pool[j] = (j < 512) ? h_hist[((size_t)1023*NB + b)*HD + j]
                            : h_hist[((size_t)T*NB + b)*HD + (j - 512)];
    }
    __syncthreads();
    if (tid == 0){
        int c = 0;
        int tmp[10];
        for (int j = 0; j < 10; ++j) tmp[j] = 0;
        for (int t = 0; t < 1024; ++t){
            if (flag[t]){ if (c < 10) tmp[c] = t; c++; }
        }
        for (int j = 0; j < 10; ++j) sel[b*12 + j] = tmp[j];
        sel[b*12 + 10] = c;
        sel[b*12 + 11] = 0;
    }
    __syncthreads();
    for (int n = tid; n < 1024; n += 256){
        float acc = bgv[n];
        const float* wr = wgm + (size_t)n*1024;
        for (int k = 0; k < 1024; k += 4){
            acc += wr[k]*pool[k] + wr[k+1]*pool[k+1] + wr[k+2]*pool[k+2] + wr[k+3]*pool[k+3];
        }
        gctx[b*1024 + n] = acc;
    }
}

// ---------------------------------------------------------------------------
// Decoder: one block per (b,slot)
// ---------------------------------------------------------------------------
__global__ void decode(const float* __restrict__ ws_, const float* __restrict__ wd1,
                       const float* __restrict__ bd1, const float* __restrict__ wd2,
                       const float* __restrict__ bd2, float* __restrict__ dout)
{
    const float* h_hist = ws_ + OFF_HH;
    const float* gctx   = ws_ + OFF_GCTX;
    const int* sel = (const int*)(ws_ + OFF_SEL);
    int blk = blockIdx.x;
    int b = blk / 10, slot = blk % 10;
    int tid = threadIdx.x;
    int count = sel[b*12 + 10];
    int nval = count < 10 ? count : 10;
    bool empty = (count == 0);
    float* outp = dout + (size_t)(b*10 + slot)*512;
    if (slot >= nval && !(empty && slot == 0)){
        for (int n = tid; n < 512; n += 256) outp[n] = 0.0f;
        return;
    }
    __shared__ float row[1024];
    __shared__ float dh[512];
    if (empty){
        for (int j = tid; j < 1024; j += 256) row[j] = gctx[b*1024 + j];
    } else {
        int t = sel[b*12 + slot];
        for (int j = tid; j < 1024; j += 256)
            row[j] = (j < 512) ? h_hist[((size_t)t*NB + b)*HD + j]
                               : h_hist[((size_t)(T + t)*NB + b)*HD + (j-512)];
    }
    __syncthreads();
    for (int d = tid; d < 512; d += 256){
        float acc = bd1[d];
        const float* wr = wd1 + (size_t)d*1024;
        for (int k = 0; k < 1024; ++k) acc += wr[k]*row[k];
        dh[d] = fmaxf(acc, 0.0f);
    }
    __syncthreads();
    for (int n = tid; n < 512; n += 256){
        float acc = bd2[n];
        const float* wr = wd2 + (size_t)n*512;
        for (int k = 0; k < 512; ++k) acc += wr[k]*dh[k];
        outp[n] = acc;
    }
}

extern "C" void kernel_launch(void* const* d_in, const int* in_sizes, int n_in,
                              void* d_out, int out_size, void* d_ws, size_t ws_size,
                              hipStream_t stream)
{
    const int*   instr = (const int*)d_in[0];
    const float* emb   = (const float*)d_in[1];
    const float* wih_f = (const float*)d_in[2];
    const float* whh_f = (const float*)d_in[3];
    const float* bih_f = (const float*)d_in[4];
    const float* bhh_f = (const float*)d_in[5];
    const float* wih_b = (const float*)d_in[6];
    const float* whh_b = (const float*)d_in[7];
    const float* bih_b = (const float*)d_in[8];
    const float* bhh_b = (const float*)d_in[9];
    const float* wg_   = (const float*)d_in[10];
    const float* bg_   = (const float*)d_in[11];
    const float* ws1   = (const float*)d_in[12];
    const float* bs1   = (const float*)d_in[13];
    const float* ws2   = (const float*)d_in[14];
    const float* bs2   = (const float*)d_in[15];
    const float* wd1   = (const float*)d_in[16];
    const float* bd1   = (const float*)d_in[17];
    const float* wd2   = (const float*)d_in[18];
    const float* bd2   = (const float*)d_in[19];
    float* out = (float*)d_out;
    float* ws  = (float*)d_ws;

    // zero the per-wg step flags (captured as a memset node; re-runs every replay)
    hipMemsetAsync(d_ws, 0, 1024, stream);

    hipLaunchKernelGGL(lstm_kernel, dim3(256), dim3(512), 0, stream,
                       instr, emb, wih_f, whh_f, bih_f, bhh_f,
                       wih_b, whh_b, bih_b, bhh_b, ws);
    hipLaunchKernelGGL(seg_gemm, dim3(256, 8), dim3(256), 0, stream, ws, ws1, bs1);
    hipLaunchKernelGGL(seg_score, dim3(4096), dim3(256), 0, stream, ws, ws2, bs2, out);
    hipLaunchKernelGGL(select_gctx, dim3(16), dim3(256), 0, stream, ws, wg_, bg_);
    hipLaunchKernelGGL(decode, dim3(160), dim3(256), 0, stream, ws, wd1, bd1, wd2, bd2, out);
}